// Round 2
// baseline (235.380 us; speedup 1.0000x reference)
//
#include <hip/hip_runtime.h>
#include <hip/hip_bf16.h>
#include <cstdint>
#include <cstddef>

// 20-qubit statevector simulator.
// Convention: flat index bit position p holds qubit q = 19 - p  (C-order of
// a (2,)*20 tensor: qubit q has stride 2^(19-q)).
//
// Circuit per block k: U3(k,q) on each qubit q, then CU3(k,q) on (c=q, t=q+1 mod 20)
// in ring order. Fused into 5 passes of 5-qubit register-resident windows:
//   A: qubits {0,1,2,3,4}    U3 on all 5,      CU3 (0,1)(1,2)(2,3)(3,4)
//   B: qubits {4,5,6,7,8}    U3 on 5,6,7,8,    CU3 (4,5)(5,6)(6,7)(7,8)
//   C: qubits {8..12}        U3 on 9..12,      CU3 (8,9)...(11,12)
//   D: qubits {12..16}       U3 on 13..16,     CU3 (12,13)...(15,16)
//   E: qubits {16,17,18,19,0} U3 on 17,18,19,  CU3 (16,17)(17,18)(18,19)(19,0)
// Reordering is valid: each U3 is applied before any ring gate touching its
// qubit, ring gates stay in exact ring order, and U3s commute with
// disjoint-qubit ring gates.

#define N_STATE (1u << 20)

__device__ __forceinline__ float2 cmadd2(float2 m0, float2 a0, float2 m1, float2 a1) {
  // m0*a0 + m1*a1 (complex)
  float2 r;
  r.x = m0.x * a0.x - m0.y * a0.y + m1.x * a1.x - m1.y * a1.y;
  r.y = m0.x * a0.y + m0.y * a0.x + m1.x * a1.y + m1.y * a1.x;
  return r;
}

__global__ void initpsi(float2* psi) {
  unsigned i = blockIdx.x * blockDim.x + threadIdx.x;
  psi[i] = make_float2(i == 0 ? 1.f : 0.f, 0.f);
}

// mats layout: gates 0..59 = U3 (g = k*20 + q); 60..119 = CU3 target-block U
// (g = 60 + k*20 + control_q). Each gate: 4 float2 {m00,m01,m10,m11}.
__global__ void matgen(const float* __restrict__ u3p,
                       const float* __restrict__ cu3p,
                       float2* __restrict__ mats, float* accum) {
  int g = threadIdx.x;
  if (g == 0) *accum = 0.f;
  if (g >= 120) return;
  const float* src = (g < 60) ? (u3p + g * 3) : (cu3p + (g - 60) * 3);
  float th = src[0];
  float ph = src[1];
  float la = src[2];
  float ct = cosf(0.5f * th), st = sinf(0.5f * th);
  float2* m = mats + g * 4;
  m[0] = make_float2(ct, 0.f);                          // cos(t/2)
  m[1] = make_float2(-cosf(la) * st, -sinf(la) * st);   // -e^{i lam} sin
  m[2] = make_float2(cosf(ph) * st, sinf(ph) * st);     //  e^{i phi} sin
  m[3] = make_float2(cosf(ph + la) * ct, sinf(ph + la) * ct); // e^{i(phi+lam)} cos
}

// One fused pass: 5 qubits at bit positions P0..P4 (local qubit i <-> bit i of
// the 32-amplitude register index; circuit qubit = 19 - P[i]).
// MASK bit i: apply U3 to local qubit i. Then CU3 on local pairs (0,1)..(3,4).
template <int P0, int P1, int P2, int P3, int P4, int MASK>
__global__ __launch_bounds__(64) void pass_kernel(float2* __restrict__ psi,
                                                  const float2* __restrict__ mats,
                                                  int k) {
  constexpr int P[5] = {P0, P1, P2, P3, P4};
  constexpr unsigned GM =
      (1u << P0) | (1u << P1) | (1u << P2) | (1u << P3) | (1u << P4);

  unsigned tid = blockIdx.x * 64u + threadIdx.x;
  // Scatter tid's 15 bits into the 15 non-gate bit positions (ascending).
  unsigned idx = 0, t = tid;
#pragma unroll
  for (int b = 0; b < 20; b++) {
    if (!((GM >> b) & 1u)) {
      idx |= (t & 1u) << b;
      t >>= 1u;
    }
  }

  float2 v[32];
#pragma unroll
  for (int j = 0; j < 32; j++) {
    unsigned off = ((j & 1) ? (1u << P0) : 0u) | ((j & 2) ? (1u << P1) : 0u) |
                   ((j & 4) ? (1u << P2) : 0u) | ((j & 8) ? (1u << P3) : 0u) |
                   ((j & 16) ? (1u << P4) : 0u);
    v[j] = psi[idx | off];
  }

  // U3 gates (new[b'] = sum_b m[b'][b] old[b] on local qubit i)
#pragma unroll
  for (int i = 0; i < 5; i++) {
    if ((MASK >> i) & 1) {  // compile-time foldable; register indices static
      const float2* m = mats + (unsigned)(k * 20 + (19 - P[i])) * 4u;
      float2 m00 = m[0], m01 = m[1], m10 = m[2], m11 = m[3];
#pragma unroll
      for (int j = 0; j < 32; j++) {
        if (!((j >> i) & 1)) {
          int j1 = j | (1 << i);
          float2 a0 = v[j], a1 = v[j1];
          v[j] = cmadd2(m00, a0, m01, a1);
          v[j1] = cmadd2(m10, a0, m11, a1);
        }
      }
    }
  }

  // CU3 ring segment: control = local g, target = local g+1; acts only where
  // control bit == 1.
#pragma unroll
  for (int g = 0; g < 4; g++) {
    const float2* m = mats + (unsigned)(60 + k * 20 + (19 - P[g])) * 4u;
    float2 u00 = m[0], u01 = m[1], u10 = m[2], u11 = m[3];
#pragma unroll
    for (int j = 0; j < 32; j++) {
      if (((j >> g) & 1) && !((j >> (g + 1)) & 1)) {
        int j1 = j | (1 << (g + 1));
        float2 a0 = v[j], a1 = v[j1];
        v[j] = cmadd2(u00, a0, u01, a1);
        v[j1] = cmadd2(u10, a0, u11, a1);
      }
    }
  }

#pragma unroll
  for (int j = 0; j < 32; j++) {
    unsigned off = ((j & 1) ? (1u << P0) : 0u) | ((j & 2) ? (1u << P1) : 0u) |
                   ((j & 4) ? (1u << P2) : 0u) | ((j & 8) ? (1u << P3) : 0u) |
                   ((j & 16) ? (1u << P4) : 0u);
    psi[idx | off] = v[j];
  }
}

__device__ __forceinline__ float xval(float2 a) {
  float p = a.x * a.x + a.y * a.y;
  // (beta * tanh(gamma * 2^19 * p))^alpha, beta=0.8 gamma=0.1 alpha=0.3
  return powf(0.8f * tanhf(52428.8f * p), 0.3f);
}

__global__ void sumx(const float2* __restrict__ psi, float* accum) {
  unsigned i0 = blockIdx.x * blockDim.x + threadIdx.x;
  unsigned stride = gridDim.x * blockDim.x;
  float s = 0.f;
  for (unsigned i = i0; i < N_STATE; i += stride) s += xval(psi[i]);
#pragma unroll
  for (int o = 32; o > 0; o >>= 1) s += __shfl_down(s, o);
  __shared__ float wsum[4];
  int wid = threadIdx.x >> 6;
  if ((threadIdx.x & 63) == 0) wsum[wid] = s;
  __syncthreads();
  if (threadIdx.x == 0) {
    atomicAdd(accum, wsum[0] + wsum[1] + wsum[2] + wsum[3]);
  }
}

__global__ void finalize(const float2* __restrict__ psi,
                         const float* __restrict__ accum,
                         float* __restrict__ out, int n) {
  int i = blockIdx.x * blockDim.x + threadIdx.x;
  if (i >= n) return;
  float mean = *accum * (1.f / 1048576.f);
  out[i] = xval(psi[i]) - mean;
}

extern "C" void kernel_launch(void* const* d_in, const int* in_sizes, int n_in,
                              void* d_out, int out_size, void* d_ws,
                              size_t ws_size, hipStream_t stream) {
  const float* u3p = (const float*)d_in[0];
  const float* cu3p = (const float*)d_in[1];
  float* out = (float*)d_out;

  char* ws = (char*)d_ws;
  float2* psi = (float2*)ws;                                  // 8 MB
  float2* mats = (float2*)(ws + (size_t)8 * 1024 * 1024);     // 3840 B
  float* accum = (float*)(ws + (size_t)8 * 1024 * 1024 + 4096);

  initpsi<<<4096, 256, 0, stream>>>(psi);
  matgen<<<1, 128, 0, stream>>>(u3p, cu3p, mats, accum);

  for (int k = 0; k < 3; k++) {
    pass_kernel<19, 18, 17, 16, 15, 0b11111><<<512, 64, 0, stream>>>(psi, mats, k);
    pass_kernel<15, 14, 13, 12, 11, 0b11110><<<512, 64, 0, stream>>>(psi, mats, k);
    pass_kernel<11, 10, 9, 8, 7, 0b11110><<<512, 64, 0, stream>>>(psi, mats, k);
    pass_kernel<7, 6, 5, 4, 3, 0b11110><<<512, 64, 0, stream>>>(psi, mats, k);
    pass_kernel<3, 2, 1, 0, 19, 0b01110><<<512, 64, 0, stream>>>(psi, mats, k);
  }

  sumx<<<1024, 256, 0, stream>>>(psi, accum);
  finalize<<<4096, 256, 0, stream>>>(psi, accum, out, out_size);
}

// Round 3
// 155.209 us; speedup vs baseline: 1.5165x; 1.5165x over previous
//
#include <hip/hip_runtime.h>
#include <cstdint>
#include <cstddef>

// 20-qubit statevector sim, 3 blocks of [U3 layer + CU3 ring (0,1)..(19,0)].
//
// 6 LDS-tile passes (2 per circuit block), each over 256 tiles of 2^12 amps:
//   S1: U3 q0..q11,  CU3 (0,1)..(10,11)   — 12-qubit window
//   S2: U3 q12..q19, CU3 (11,12)..(19,0)  — 10-qubit window + 2 filler qubits
// Ring order is preserved exactly (prefix then suffix); U3s are applied
// before any ring gate touching their qubit; all other reorderings are
// between disjoint-qubit gates (commute).
//
// Layout ping-pong: passes write a permuted qubit->bit layout so the NEXT
// pass's window is always the low 12 bits (contiguous 32 KB tile reads):
//   L_B (input of S1): b0..b2=q0..q2, b3=q11, b4..b11=q3..q10, b12..19=q12..q19
//   L_A (input of S2): b0..b2=q0..q2, b3..b11=q11..q19,        b12..19=q3..q10
// Both pass types then write G_out = (L&15) | tile<<4 | (L>>4)<<12 — full
// 128 B runs per thread. Final pass scatters to the reference layout
// (qubit q -> bit 19-q) via bit-reversal while computing the readout.

#define PHYS(L) ((L) + 2u * ((L) >> 4))  // LDS pad: +2 float2 per 16 (bank spread, keeps 16B align)

__device__ __forceinline__ float2 cmadd2(float2 m0, float2 a0, float2 m1, float2 a1) {
  float2 r;
  r.x = m0.x * a0.x - m0.y * a0.y + m1.x * a1.x - m1.y * a1.y;
  r.y = m0.x * a0.y + m0.y * a0.x + m1.x * a1.y + m1.y * a1.x;
  return r;
}

// mats: gates 0..59 = U3 (g=k*20+q); 60..119 = CU3 target-block U (g=60+k*20+c).
__global__ void matgen(const float* __restrict__ u3p, const float* __restrict__ cu3p,
                       float2* __restrict__ mats, float* accum) {
  int g = threadIdx.x;
  if (g == 0) *accum = 0.f;
  if (g >= 120) return;
  const float* src = (g < 60) ? (u3p + g * 3) : (cu3p + (g - 60) * 3);
  float th = src[0], ph = src[1], la = src[2];
  float ct = cosf(0.5f * th), st = sinf(0.5f * th);
  float2* m = mats + g * 4;
  m[0] = make_float2(ct, 0.f);
  m[1] = make_float2(-cosf(la) * st, -sinf(la) * st);
  m[2] = make_float2(cosf(ph) * st, sinf(ph) * st);
  m[3] = make_float2(cosf(ph + la) * ct, sinf(ph + la) * ct);
}

template <unsigned MASK>
__device__ __forceinline__ unsigned pdep12(unsigned v) {
  unsigned r = 0; int k = 0;
#pragma unroll
  for (int b = 0; b < 12; b++)
    if ((MASK >> b) & 1u) { r |= ((v >> k) & 1u) << b; k++; }
  return r;
}

template <int R0, int R1, int R2, int R3>
__device__ __forceinline__ void loadWin(const float2* lds, unsigned t, float2* v) {
  constexpr unsigned RM = (1u << R0) | (1u << R1) | (1u << R2) | (1u << R3);
  constexpr unsigned NM = 0xFFFu & ~RM;
  unsigned base = pdep12<NM>(t);
#pragma unroll
  for (int j = 0; j < 16; j++) {
    unsigned L = base | ((j & 1) ? (1u << R0) : 0u) | ((j & 2) ? (1u << R1) : 0u) |
                 ((j & 4) ? (1u << R2) : 0u) | ((j & 8) ? (1u << R3) : 0u);
    v[j] = lds[PHYS(L)];
  }
}

template <int R0, int R1, int R2, int R3>
__device__ __forceinline__ void storeWin(float2* lds, unsigned t, const float2* v) {
  constexpr unsigned RM = (1u << R0) | (1u << R1) | (1u << R2) | (1u << R3);
  constexpr unsigned NM = 0xFFFu & ~RM;
  unsigned base = pdep12<NM>(t);
#pragma unroll
  for (int j = 0; j < 16; j++) {
    unsigned L = base | ((j & 1) ? (1u << R0) : 0u) | ((j & 2) ? (1u << R1) : 0u) |
                 ((j & 4) ? (1u << R2) : 0u) | ((j & 8) ? (1u << R3) : 0u);
    lds[PHYS(L)] = v[j];
  }
}

template <int BIT>
__device__ __forceinline__ void applyU3(float2* v, const float2* m) {
  float2 m00 = m[0], m01 = m[1], m10 = m[2], m11 = m[3];
#pragma unroll
  for (int j = 0; j < 16; j++)
    if (!((j >> BIT) & 1)) {
      int j1 = j | (1 << BIT);
      float2 a0 = v[j], a1 = v[j1];
      v[j] = cmadd2(m00, a0, m01, a1);
      v[j1] = cmadd2(m10, a0, m11, a1);
    }
}

template <int CB, int TB>
__device__ __forceinline__ void applyCU3(float2* v, const float2* m) {
  float2 u00 = m[0], u01 = m[1], u10 = m[2], u11 = m[3];
#pragma unroll
  for (int j = 0; j < 16; j++)
    if (((j >> CB) & 1) && !((j >> TB) & 1)) {
      int j1 = j | (1 << TB);
      float2 a0 = v[j], a1 = v[j1];
      v[j] = cmadd2(u00, a0, u01, a1);
      v[j1] = cmadd2(u10, a0, u11, a1);
    }
}

__device__ __forceinline__ float xval(float2 a) {
  float p = a.x * a.x + a.y * a.y;
  return powf(0.8f * tanhf(52428.8f * p), 0.3f);  // (beta*tanh(gamma*2^19*p))^alpha
}

// TYPE 0 = S1, 1 = S2. INIT: synthesize |0..0> instead of reading.
// FINAL: instead of writing psi, write x-values (reference order) + sum.
template <int TYPE, int INIT, int FINAL>
__global__ __launch_bounds__(256) void pass_k(const float2* __restrict__ in,
                                              float2* __restrict__ outPsi,
                                              const float2* __restrict__ mats, int k,
                                              float* __restrict__ outX,
                                              float* __restrict__ accum) {
  __shared__ float2 tile[4608];  // 4096 + pad
  __shared__ float2 M[160];      // [0..79]=U3 q0..q19 of block k; [80..159]=CU3 c0..c19
  __shared__ float wsum[4];
  unsigned t = threadIdx.x;
  unsigned blk = blockIdx.x;

  if (t < 80) M[t] = mats[k * 80 + t];
  else if (t < 160) M[t] = mats[240 + k * 80 + (t - 80)];

  if (INIT) {
#pragma unroll
    for (int m = 0; m < 16; m++) tile[18 * t + m] = make_float2(0.f, 0.f);
    if (blk == 0 && t == 0) tile[0] = make_float2(1.f, 0.f);
  } else {
    const float4* src = (const float4*)(in + ((size_t)blk << 12));
#pragma unroll
    for (int i = 0; i < 8; i++) {
      float4 x = src[t * 8 + i];
      *(float4*)&tile[18 * t + 2 * i] = x;
    }
  }
  __syncthreads();

  float2 v[16];
  if (TYPE == 0) {
    // S1 locals: l0..l2=q0..q2, l3=q11, l4..l11=q3..q10
    loadWin<0, 1, 2, 4>(tile, t, v);                       // q0,q1,q2,q3
    applyU3<0>(v, M + 0); applyU3<1>(v, M + 4);
    applyU3<2>(v, M + 8); applyU3<3>(v, M + 12);
    applyCU3<0, 1>(v, M + 80); applyCU3<1, 2>(v, M + 84); applyCU3<2, 3>(v, M + 88);
    storeWin<0, 1, 2, 4>(tile, t, v);
    __syncthreads();
    loadWin<4, 5, 6, 7>(tile, t, v);                       // q3,q4,q5,q6
    applyU3<1>(v, M + 16); applyU3<2>(v, M + 20); applyU3<3>(v, M + 24);
    applyCU3<0, 1>(v, M + 92); applyCU3<1, 2>(v, M + 96); applyCU3<2, 3>(v, M + 100);
    storeWin<4, 5, 6, 7>(tile, t, v);
    __syncthreads();
    loadWin<7, 8, 9, 10>(tile, t, v);                      // q6,q7,q8,q9
    applyU3<1>(v, M + 28); applyU3<2>(v, M + 32); applyU3<3>(v, M + 36);
    applyCU3<0, 1>(v, M + 104); applyCU3<1, 2>(v, M + 108); applyCU3<2, 3>(v, M + 112);
    storeWin<7, 8, 9, 10>(tile, t, v);
    __syncthreads();
    loadWin<10, 11, 3, 0>(tile, t, v);                     // q9,q10,q11,(q0 filler)
    applyU3<1>(v, M + 40); applyU3<2>(v, M + 44);
    applyCU3<0, 1>(v, M + 116); applyCU3<1, 2>(v, M + 120);
    storeWin<10, 11, 3, 0>(tile, t, v);
  } else {
    // S2 locals: l0..l2=q0..q2, l3..l11=q11..q19
    loadWin<3, 4, 5, 6>(tile, t, v);                       // q11,q12,q13,q14
    applyU3<1>(v, M + 48); applyU3<2>(v, M + 52); applyU3<3>(v, M + 56);
    applyCU3<0, 1>(v, M + 124); applyCU3<1, 2>(v, M + 128); applyCU3<2, 3>(v, M + 132);
    storeWin<3, 4, 5, 6>(tile, t, v);
    __syncthreads();
    loadWin<6, 7, 8, 9>(tile, t, v);                       // q14,q15,q16,q17
    applyU3<1>(v, M + 60); applyU3<2>(v, M + 64); applyU3<3>(v, M + 68);
    applyCU3<0, 1>(v, M + 136); applyCU3<1, 2>(v, M + 140); applyCU3<2, 3>(v, M + 144);
    storeWin<6, 7, 8, 9>(tile, t, v);
    __syncthreads();
    loadWin<9, 10, 11, 0>(tile, t, v);                     // q17,q18,q19,q0
    applyU3<1>(v, M + 72); applyU3<2>(v, M + 76);
    applyCU3<0, 1>(v, M + 148); applyCU3<1, 2>(v, M + 152); applyCU3<2, 3>(v, M + 156);
    storeWin<9, 10, 11, 0>(tile, t, v);
  }
  __syncthreads();

  if (!FINAL) {
    // G_out = (L&15) | blk<<4 | (L>>4)<<12, L = t<<4 | m  -> 128 B run/thread
    float2* dst = outPsi + ((size_t)blk << 4) + ((size_t)t << 12);
#pragma unroll
    for (int i = 0; i < 8; i++) {
      float4 x = *(const float4*)&tile[18 * t + 2 * i];
      *(float4*)&dst[2 * i] = x;
    }
  } else {
    // Reference layout: q0..q2 (=m0..m2) -> bits 19,18,17; q11 (=m3) -> bit 8;
    // q3..q10 (=blk) -> bits 16..9; q12..q19 (=t) -> bits 7..0.
    unsigned trev = __brev(t) >> 24;
    unsigned brev = __brev(blk) >> 24;
    unsigned baseG = trev | (brev << 9);
    float s = 0.f;
#pragma unroll
    for (int m = 0; m < 16; m++) {
      float xv = xval(tile[18 * t + m]);
      s += xv;
      unsigned G = baseG | ((m & 8) << 5) | ((m & 1) << 19) | ((m & 2) << 17) | ((m & 4) << 15);
      outX[G] = xv;
    }
#pragma unroll
    for (int o = 32; o > 0; o >>= 1) s += __shfl_down(s, o);
    if ((t & 63) == 0) wsum[t >> 6] = s;
    __syncthreads();
    if (t == 0) atomicAdd(accum, wsum[0] + wsum[1] + wsum[2] + wsum[3]);
  }
}

__global__ void fin_k(float* __restrict__ out, const float* __restrict__ accum) {
  unsigned i = blockIdx.x * blockDim.x + threadIdx.x;
  float mean = *accum * (1.f / 1048576.f);
  float4* o4 = (float4*)out;
  float4 x = o4[i];
  x.x -= mean; x.y -= mean; x.z -= mean; x.w -= mean;
  o4[i] = x;
}

extern "C" void kernel_launch(void* const* d_in, const int* in_sizes, int n_in,
                              void* d_out, int out_size, void* d_ws, size_t ws_size,
                              hipStream_t stream) {
  const float* u3p = (const float*)d_in[0];
  const float* cu3p = (const float*)d_in[1];
  float* out = (float*)d_out;

  char* ws = (char*)d_ws;
  float2* psiA = (float2*)ws;                                   // 8 MB
  float2* psiB = (float2*)(ws + (size_t)8 * 1024 * 1024);       // 8 MB
  float2* mats = (float2*)(ws + (size_t)16 * 1024 * 1024);      // 3840 B
  float* accum = (float*)(ws + (size_t)16 * 1024 * 1024 + 4096);

  matgen<<<1, 128, 0, stream>>>(u3p, cu3p, mats, accum);

  pass_k<0, 1, 0><<<256, 256, 0, stream>>>(psiA, psiA, mats, 0, out, accum);  // |0> -> S1(b0) -> A
  pass_k<1, 0, 0><<<256, 256, 0, stream>>>(psiA, psiB, mats, 0, out, accum);  // A -> S2(b0) -> B
  pass_k<0, 0, 0><<<256, 256, 0, stream>>>(psiB, psiA, mats, 1, out, accum);  // B -> S1(b1) -> A
  pass_k<1, 0, 0><<<256, 256, 0, stream>>>(psiA, psiB, mats, 1, out, accum);  // A -> S2(b1) -> B
  pass_k<0, 0, 0><<<256, 256, 0, stream>>>(psiB, psiA, mats, 2, out, accum);  // B -> S1(b2) -> A
  pass_k<1, 0, 1><<<256, 256, 0, stream>>>(psiA, psiB, mats, 2, out, accum);  // A -> S2(b2) -> x + sum

  fin_k<<<1024, 256, 0, stream>>>(out, accum);
}

// Round 4
// 143.469 us; speedup vs baseline: 1.6406x; 1.0818x over previous
//
#include <hip/hip_runtime.h>
#include <cstdint>
#include <cstddef>

// 20-qubit statevector sim, 3 blocks of [U3 layer + CU3 ring (0,1)..(19,0)].
//
// 6 passes (2 per circuit block), tile = 2048 amps (11-qubit window),
// 256 thr/block, 8 amps/thread (3-qubit register windows), grid 512
// (= 2 blocks/CU, 8 waves/CU) — R3 ran 1 wave/SIMD and was latency-bound.
//
//   S1: U3 q0..q10,  CU3 (0,1)..(9,10)    window W1 = {q0..q10}
//   S2: U3 q11..q19, CU3 (10,11)..(19,0)  window W2 = {q10..q19, q0}
//
// Layouts (bit b of the flat index <- qubit):
//   L1 (input of S1): b0=q0, b1=q10, b2..b10=q1..q9,  b11..b19=q11..q19
//   L2 (input of S2): b0=q10, b1=q0, b2..b10=q11..q19, b11..b19=q1..q9
// Both pass types: contiguous 16 KB tile loads; stores are 32 B runs
// (the two low output bits always come from in-tile qubits):
//   G_out = ((l>>1)&1) | ((l&1)<<1) | (blk<<2) | ((l>>2)<<11)   (both types!)
// Final pass: x-values staged through LDS in bit-reversed (reference) order
// -> contiguous 4 KB output runs; block-atomic sum for the mean.

#define PHYS(L) ((L) + 2u * ((L) >> 4))  // LDS pad: bank-spread, keeps 16B align

__device__ __forceinline__ float2 cmadd2(float2 m0, float2 a0, float2 m1, float2 a1) {
  float2 r;
  r.x = m0.x * a0.x - m0.y * a0.y + m1.x * a1.x - m1.y * a1.y;
  r.y = m0.x * a0.y + m0.y * a0.x + m1.x * a1.y + m1.y * a1.x;
  return r;
}

template <unsigned NM>
__device__ __forceinline__ unsigned pdep11(unsigned v) {
  unsigned r = 0; int k = 0;
#pragma unroll
  for (int b = 0; b < 11; b++)
    if ((NM >> b) & 1u) { r |= ((v >> k) & 1u) << b; k++; }
  return r;
}

template <int B>
__device__ __forceinline__ void applyU3(float2* v, const float2* m) {
  float2 m00 = m[0], m01 = m[1], m10 = m[2], m11 = m[3];
#pragma unroll
  for (int j = 0; j < 8; j++)
    if (!((j >> B) & 1)) {
      int j1 = j | (1 << B);
      float2 a0 = v[j], a1 = v[j1];
      v[j] = cmadd2(m00, a0, m01, a1);
      v[j1] = cmadd2(m10, a0, m11, a1);
    }
}

template <int C, int T>
__device__ __forceinline__ void applyCU3(float2* v, const float2* m) {
  float2 u00 = m[0], u01 = m[1], u10 = m[2], u11 = m[3];
#pragma unroll
  for (int j = 0; j < 8; j++)
    if (((j >> C) & 1) && !((j >> T) & 1)) {
      int j1 = j | (1 << T);
      float2 a0 = v[j], a1 = v[j1];
      v[j] = cmadd2(u00, a0, u01, a1);
      v[j1] = cmadd2(u10, a0, u11, a1);
    }
}

// One phase: register window = tile bits (R0,R1,R2) -> local bits 0,1,2.
// U0/U1/U2: U3 gate index on w0/w1/w2 (-1 = none). C01/C12: CU3 control gate
// index for (w0,w1)/(w1,w2) (-1 = none). M: [4g]=U3 g, [80+4c]=CU3 c.
template <int R0, int R1, int R2, int U0, int U1, int U2, int C01, int C12>
__device__ __forceinline__ void phase(float2* tile, unsigned t, const float2* M) {
  constexpr unsigned RM = (1u << R0) | (1u << R1) | (1u << R2);
  constexpr unsigned NM = 0x7FFu & ~RM;
  unsigned base = pdep11<NM>(t);
  float2 v[8];
#pragma unroll
  for (int j = 0; j < 8; j++) {
    unsigned L = base | ((j & 1) ? (1u << R0) : 0u) | ((j & 2) ? (1u << R1) : 0u) |
                 ((j & 4) ? (1u << R2) : 0u);
    v[j] = tile[PHYS(L)];
  }
  if (U0 >= 0) applyU3<0>(v, M + 4 * (U0 < 0 ? 0 : U0));
  if (U1 >= 0) applyU3<1>(v, M + 4 * (U1 < 0 ? 0 : U1));
  if (U2 >= 0) applyU3<2>(v, M + 4 * (U2 < 0 ? 0 : U2));
  if (C01 >= 0) applyCU3<0, 1>(v, M + 80 + 4 * (C01 < 0 ? 0 : C01));
  if (C12 >= 0) applyCU3<1, 2>(v, M + 80 + 4 * (C12 < 0 ? 0 : C12));
#pragma unroll
  for (int j = 0; j < 8; j++) {
    unsigned L = base | ((j & 1) ? (1u << R0) : 0u) | ((j & 2) ? (1u << R1) : 0u) |
                 ((j & 4) ? (1u << R2) : 0u);
    tile[PHYS(L)] = v[j];
  }
}

__device__ __forceinline__ float xval(float2 a) {
  float p = a.x * a.x + a.y * a.y;
  return powf(0.8f * tanhf(52428.8f * p), 0.3f);  // (beta*tanh(gamma*2^19*p))^alpha
}

__device__ __forceinline__ unsigned rev9(unsigned x) { return __brev(x) >> 23; }

// TYPE 0 = S1, 1 = S2; INIT synthesizes |0..0>; FINAL emits x + sum.
template <int TYPE, int INIT, int FINAL>
__global__ __launch_bounds__(256) void pass_k(const float2* __restrict__ in,
                                              float2* __restrict__ outPsi,
                                              const float* __restrict__ u3p,
                                              const float* __restrict__ cu3p, int k,
                                              float* __restrict__ outX,
                                              float* __restrict__ accum) {
  __shared__ float2 tile[2304];  // PHYS(2047)=2301
  __shared__ float2 M[160];      // [0..79] U3 q0..q19 (blk k); [80..159] CU3 c0..c19
  __shared__ float wsum[4];
  unsigned t = threadIdx.x, b = blockIdx.x;

  if (INIT && b != 0) {
    // all-zero tile: just write zeros to the scattered output runs
    float4 z = make_float4(0.f, 0.f, 0.f, 0.f);
    float4* o4 = (float4*)outPsi;
#pragma unroll
    for (int hh = 0; hh < 2; hh++) {
      unsigned h = 2 * t + hh;
      unsigned f4 = (b << 1) | (h << 10);
      o4[f4] = z; o4[f4 + 1] = z;
    }
    return;
  }

  // gate matrices for circuit block k (threads 0..19: U3; 64..83: CU3)
  if (t < 20) {
    const float* s = u3p + (k * 20 + t) * 3;
    float th = s[0], ph = s[1], la = s[2];
    float ct = cosf(0.5f * th), st = sinf(0.5f * th);
    float2* m = M + 4 * t;
    m[0] = make_float2(ct, 0.f);
    m[1] = make_float2(-cosf(la) * st, -sinf(la) * st);
    m[2] = make_float2(cosf(ph) * st, sinf(ph) * st);
    m[3] = make_float2(cosf(ph + la) * ct, sinf(ph + la) * ct);
  } else if (t >= 64 && t < 84) {
    int c = t - 64;
    const float* s = cu3p + (k * 20 + c) * 3;
    float th = s[0], ph = s[1], la = s[2];
    float ct = cosf(0.5f * th), st = sinf(0.5f * th);
    float2* m = M + 80 + 4 * c;
    m[0] = make_float2(ct, 0.f);
    m[1] = make_float2(-cosf(la) * st, -sinf(la) * st);
    m[2] = make_float2(cosf(ph) * st, sinf(ph) * st);
    m[3] = make_float2(cosf(ph + la) * ct, sinf(ph + la) * ct);
  }

  if (INIT) {  // b == 0 here
#pragma unroll
    for (int m = 0; m < 8; m++) tile[PHYS(8 * t + m)] = make_float2(0.f, 0.f);
    if (t == 0) { tile[PHYS(0)] = make_float2(1.f, 0.f); *accum = 0.f; }
  } else {
    const float4* src = (const float4*)(in + ((size_t)b << 11));
#pragma unroll
    for (int i = 0; i < 4; i++) {
      float4 x = src[t * 4 + i];
      *(float4*)&tile[PHYS(8 * t + 2 * i)] = x;
    }
  }
  __syncthreads();

  // 5 phases; bit triples identical for both pass types (chain layout is
  // symmetric by construction). Gate tables:
  //   S1: P1 U3{0,1,2} C{0,1};  P2..P5: U3{2p-1,2p} C{2p-2,2p-1}
  //   S2: P1 U3{-,11,12} C{10,11}; ... P5: U3{-,19,-} C{18,19}
  if (TYPE == 0) {
    phase<0, 2, 3, 0, 1, 2, 0, 1>(tile, t, M); __syncthreads();
    phase<3, 4, 5, -1, 3, 4, 2, 3>(tile, t, M); __syncthreads();
    phase<5, 6, 7, -1, 5, 6, 4, 5>(tile, t, M); __syncthreads();
    phase<7, 8, 9, -1, 7, 8, 6, 7>(tile, t, M); __syncthreads();
    phase<9, 10, 1, -1, 9, 10, 8, 9>(tile, t, M); __syncthreads();
  } else {
    phase<0, 2, 3, -1, 11, 12, 10, 11>(tile, t, M); __syncthreads();
    phase<3, 4, 5, -1, 13, 14, 12, 13>(tile, t, M); __syncthreads();
    phase<5, 6, 7, -1, 15, 16, 14, 15>(tile, t, M); __syncthreads();
    phase<7, 8, 9, -1, 17, 18, 16, 17>(tile, t, M); __syncthreads();
    phase<9, 10, 1, -1, 19, -1, 18, 19>(tile, t, M); __syncthreads();
  }

  if (!FINAL) {
    // G_out = ((l>>1)&1) | ((l&1)<<1) | (b<<2) | ((l>>2)<<11); 32 B runs.
    float4* o4 = (float4*)outPsi;
#pragma unroll
    for (int hh = 0; hh < 2; hh++) {
      unsigned h = 2 * t + hh;
      float2 a0 = tile[PHYS(4 * h)], a1 = tile[PHYS(4 * h + 1)];
      float2 a2 = tile[PHYS(4 * h + 2)], a3 = tile[PHYS(4 * h + 3)];
      unsigned f4 = (b << 1) | (h << 10);
      o4[f4] = make_float4(a0.x, a0.y, a2.x, a2.y);      // G offsets 0,1
      o4[f4 + 1] = make_float4(a1.x, a1.y, a3.x, a3.y);  // G offsets 2,3
    }
  } else {
    // Reference index R: qubit q -> bit 19-q.
    // Amp (L2): q10=l0, q0=l1, q11+j=l(2+j), q1+j=b_j.
    // In-tile R bits: bit19=l1, bit9=l0, bits8..0=rev9(l>>2); base=rev9(b)<<10.
    float xv[8]; float s = 0.f;
#pragma unroll
    for (int m = 0; m < 8; m++) { xv[m] = xval(tile[PHYS(8 * t + m)]); s += xv[m]; }
    __syncthreads();
    float* xb = (float*)tile;  // reuse LDS as float[2048] staging
#pragma unroll
    for (int m = 0; m < 8; m++) {
      unsigned l = 8 * t + m;
      unsigned p = (((l >> 1) & 1u) << 10) | ((l & 1u) << 9) | rev9(l >> 2);
      xb[p] = xv[m];
    }
    __syncthreads();
    const float4* xb4 = (const float4*)xb;
    float4* o4 = (float4*)outX;
    unsigned base0 = rev9(b) << 8;              // float4 units
    o4[base0 + t] = xb4[t];                     // R bit19 = 0 run
    o4[(1u << 17) + base0 + t] = xb4[256 + t];  // R bit19 = 1 run
#pragma unroll
    for (int o = 32; o > 0; o >>= 1) s += __shfl_down(s, o);
    if ((t & 63) == 0) wsum[t >> 6] = s;
    __syncthreads();
    if (t == 0) atomicAdd(accum, wsum[0] + wsum[1] + wsum[2] + wsum[3]);
  }
}

__global__ void fin_k(float* __restrict__ out, const float* __restrict__ accum) {
  unsigned i = blockIdx.x * blockDim.x + threadIdx.x;
  float mean = *accum * (1.f / 1048576.f);
  float4* o4 = (float4*)out;
  float4 x = o4[i];
  x.x -= mean; x.y -= mean; x.z -= mean; x.w -= mean;
  o4[i] = x;
}

extern "C" void kernel_launch(void* const* d_in, const int* in_sizes, int n_in,
                              void* d_out, int out_size, void* d_ws, size_t ws_size,
                              hipStream_t stream) {
  const float* u3p = (const float*)d_in[0];
  const float* cu3p = (const float*)d_in[1];
  float* out = (float*)d_out;

  char* ws = (char*)d_ws;
  float2* psiA = (float2*)ws;                                   // 8 MB
  float2* psiB = (float2*)(ws + (size_t)8 * 1024 * 1024);       // 8 MB
  float* accum = (float*)(ws + (size_t)16 * 1024 * 1024);

  pass_k<0, 1, 0><<<512, 256, 0, stream>>>(psiA, psiA, u3p, cu3p, 0, out, accum);
  pass_k<1, 0, 0><<<512, 256, 0, stream>>>(psiA, psiB, u3p, cu3p, 0, out, accum);
  pass_k<0, 0, 0><<<512, 256, 0, stream>>>(psiB, psiA, u3p, cu3p, 1, out, accum);
  pass_k<1, 0, 0><<<512, 256, 0, stream>>>(psiA, psiB, u3p, cu3p, 1, out, accum);
  pass_k<0, 0, 0><<<512, 256, 0, stream>>>(psiB, psiA, u3p, cu3p, 2, out, accum);
  pass_k<1, 0, 1><<<512, 256, 0, stream>>>(psiA, psiB, u3p, cu3p, 2, out, accum);
  fin_k<<<1024, 256, 0, stream>>>(out, accum);
}